// Round 3
// baseline (492.421 us; speedup 1.0000x reference)
//
#include <hip/hip_runtime.h>

// Unfold (im2col) disguised as depthwise conv with eye(9) kernels.
// x: [16, 64, 112, 112] f32 -> out: [16, 64*9, 112, 112] f32
// out[n, c*9 + (kr*3+kc), h, w] = x[n, c, h+kr-1, w+kc-1] (zero pad)
//
// R6: LDS-staged plane-burst writes.
// Evidence: R4 (block-sequential plane writes) lifted effective BW
// 2.82 -> 3.97 TB/s over R3 (9 interleaved streams/wave) but paid 2x
// traffic re-reading the input 9x through a write-churned L2. R6 keeps
// R4's write shape and kills the re-read: each block stages a 30-row
// halo'd input slab (13.4 KB, contiguous in global) into LDS ONCE, then
// emits the 9 shifted output tiles one plane at a time as pure
// sequential write bursts (1 KB/wave-store, 12.5 KB/block/plane).
// Reads ~55 MB total, writes 462 MB, zero global reads in the write loop.
//
// Block = (n, c, h-chunk of 28 rows). 16*64*4 = 4096 blocks x 256 thr.
// LDS = 30 rows x 112 floats = 13,440 B -> 8 blocks/CU (32-wave cap).
// LDS reads: ds_read_b128 over contiguous addresses (conflict-free) +
// stride-16B edge scalars (cheap 4-way, ~2 per 3 planes).

#define NN 16
#define CC 64
#define HH 112
#define WW 112
#define W4C 28                  // float4 per row
#define PLANE  (HH * WW)        // 12544 floats
#define PLANE4 (HH * W4C)       // 3136 float4
#define RPB 28                  // output rows per block
#define LROWS (RPB + 2)         // 30 LDS rows (halo)
#define LDS_F4 (LROWS * W4C)    // 840 float4 in LDS
#define TPB 256

typedef float v4f __attribute__((ext_vector_type(4)));

__global__ __launch_bounds__(TPB) void unfold9_lds(const float* __restrict__ x,
                                                   float* __restrict__ out) {
    __shared__ float lds[LROWS * WW];   // 13,440 B, rows 448B (16B-aligned)

    unsigned bid = blockIdx.x;
    unsigned q   = bid & 3u;            // h-chunk 0..3
    unsigned pb  = bid >> 2;            // n*64 + c
    unsigned h0  = q * RPB;

    const v4f* __restrict__ xp4 = reinterpret_cast<const v4f*>(x) + (size_t)pb * PLANE4;
    v4f* lds4 = reinterpret_cast<v4f*>(lds);

    // ---- Stage: rows [h0-1, h0+28] of the input plane (zero-clamped). ----
    // Global float4 index within plane for LDS slot t: g = (h0-1)*28 + t.
    int gstart = (int)h0 * W4C - W4C;
    for (unsigned t = threadIdx.x; t < LDS_F4; t += TPB) {
        int g = gstart + (int)t;
        v4f v = (v4f){0.f, 0.f, 0.f, 0.f};
        if (g >= 0 && g < PLANE4) v = xp4[g];
        lds4[t] = v;
    }
    __syncthreads();

    // ---- Emit: 9 planes, one at a time, sequential write bursts. ----
    // out[h][w] = lds[(h - h0 + 1 + dh)][w + dw]   (dh,dw in {-1,0,1})
    size_t obase = (size_t)pb * 9u * PLANE + (size_t)h0 * WW;
#pragma unroll
    for (int j = 0; j < 9; ++j) {
        const int dh = j / 3 - 1;
        const int dw = j % 3 - 1;
        float* __restrict__ op = out + obase + (size_t)j * PLANE;
        for (unsigned pos = threadIdx.x; pos < RPB * W4C; pos += TPB) {
            unsigned qr = pos / W4C;           // 0..27
            unsigned w4 = pos % W4C;
            unsigned r  = qr + 1u + (unsigned)(dh + 0);  // dh in {-1,0,1} -> 0..29
            r = (unsigned)((int)qr + 1 + dh);
            const float* row = lds + r * WW;
            v4f m = *reinterpret_cast<const v4f*>(row + w4 * 4u);
            v4f v;
            if (dw == 0) {
                v = m;
            } else if (dw < 0) {               // out[w] = x[w-1]
                float l = (w4 > 0u) ? row[w4 * 4u - 1u] : 0.f;
                v = (v4f){l, m.x, m.y, m.z};
            } else {                           // out[w] = x[w+1]
                float rr = (w4 < W4C - 1u) ? row[w4 * 4u + 4u] : 0.f;
                v = (v4f){m.y, m.z, m.w, rr};
            }
            *reinterpret_cast<v4f*>(op + (size_t)pos * 4u) = v;
        }
    }
}

extern "C" void kernel_launch(void* const* d_in, const int* in_sizes, int n_in,
                              void* d_out, int out_size, void* d_ws, size_t ws_size,
                              hipStream_t stream) {
    const float* x = (const float*)d_in[0];
    // d_in[1] (eye-kernel weight) is baked into the index math.
    float* out = (float*)d_out;

    const unsigned blocks = NN * CC * 4u;   // 4096
    unfold9_lds<<<blocks, TPB, 0, stream>>>(x, out);
}